// Round 13
// baseline (183.460 us; speedup 1.0000x reference)
//
#include <hip/hip_runtime.h>
#include <hip/hip_bf16.h>
#include <cstdint>
#include <cstddef>

using bf16 = __hip_bfloat16;
typedef __attribute__((ext_vector_type(8))) short short8;
typedef __attribute__((ext_vector_type(4))) float f32x4;
typedef __attribute__((ext_vector_type(4))) unsigned int u32x4;

#define MFMA16(a, b, c) __builtin_amdgcn_mfma_f32_16x16x32_bf16((a), (b), (c), 0, 0, 0)

static constexpr int S = 2048;
static constexpr int E = 2048;
static constexpr int H = 16;
static constexpr int KVH = 4;
static constexpr int Dh = 128;
static constexpr int NQKV = 3072;        // 2048 q + 512 k + 512 v
static constexpr float ATTN_SCALE = 0.08838834764831845f; // 1/sqrt(128)
static constexpr float NEG_BIG = -1e30f; // finite -inf surrogate

__device__ __forceinline__ short f2bs(float f) {
  __hip_bfloat16 h = __float2bfloat16(f);
  return *reinterpret_cast<short*>(&h);
}

// pack two floats to a bf16 pair (lo -> bits[15:0], hi -> bits[31:16]).
// (inline-asm v_cvt_pk_bf16_f32 produced NaN on gfx950 — round 11. Keep C++.)
__device__ __forceinline__ unsigned int pack_bf16(float lo, float hi) {
  return ((unsigned int)(unsigned short)f2bs(hi) << 16) |
         (unsigned int)(unsigned short)f2bs(lo);
}

__device__ __forceinline__ void gload_lds16(const void* g, void* l) {
  __builtin_amdgcn_global_load_lds(
      (const __attribute__((address_space(1))) unsigned int*)g,
      (__attribute__((address_space(3))) unsigned int*)l,
      16, 0, 0);
}

// ---------------- fused f32 -> bf16 convert for all 5 inputs -------------------
// segments (elems): x 4M | Wq 4M | Wk 1M | Wv 1M | Wo 4M  = 14M total
__global__ void cvt_all(const float* __restrict__ x,  const float* __restrict__ wq,
                        const float* __restrict__ wk, const float* __restrict__ wv,
                        const float* __restrict__ wo,
                        bf16* __restrict__ xb, bf16* __restrict__ wcat,
                        bf16* __restrict__ wob) {
  const long M1 = 4l << 20, M2 = 8l << 20, M3 = 9l << 20, M4 = 10l << 20, M5 = 14l << 20;
  long i = ((long)blockIdx.x * 256 + threadIdx.x) * 8;
  if (i >= M5) return;
  const float* src;
  bf16* dst;
  if (i < M1)      { src = x  + i;        dst = xb + i; }
  else if (i < M2) { src = wq + (i - M1); dst = wcat + (i - M1); }
  else if (i < M3) { src = wk + (i - M2); dst = wcat + 2048l * 2048 + (i - M2); }
  else if (i < M4) { src = wv + (i - M3); dst = wcat + 2560l * 2048 + (i - M3); }
  else             { src = wo + (i - M4); dst = wob + (i - M4); }
  const float4* s4 = reinterpret_cast<const float4*>(src);
  float4 a = s4[0];
  float4 b = s4[1];
  short8 o;
  o[0] = f2bs(a.x); o[1] = f2bs(a.y); o[2] = f2bs(a.z); o[3] = f2bs(a.w);
  o[4] = f2bs(b.x); o[5] = f2bs(b.y); o[6] = f2bs(b.z); o[7] = f2bs(b.w);
  *reinterpret_cast<short8*>(dst) = o;
}

// ---------------- GEMM (128x128): C[m][n] = sum_k A[m][k] * B[n][k] ------------
template <bool OUT_F32>
__global__ __launch_bounds__(256, 2) void gemm_nt(const bf16* __restrict__ A,
                                                  const bf16* __restrict__ B,
                                                  void* __restrict__ Cout,
                                                  int M, int N, int K) {
  __shared__ bf16 As[128 * 32];
  __shared__ bf16 Bs[128 * 32];
  const int tid = threadIdx.x;
  const int lane = tid & 63;
  const int wv = tid >> 6;
  const int lr = lane & 15, lq = lane >> 4;
  const int wm = (wv >> 1) * 64, wn = (wv & 1) * 64;

  const int nwgx = M >> 7;
  const int nwg = (M >> 7) * (N >> 7);
  const int id = blockIdx.x + gridDim.x * blockIdx.y;
  const int sid = (id & 7) * (nwg >> 3) + (id >> 3);   // XCD swizzle (bijective)
  const int bm = (sid % nwgx) * 128, bn = (sid / nwgx) * 128;

  f32x4 acc[4][4] = {};

  for (int k0 = 0; k0 < K; k0 += 32) {
    __syncthreads();
    for (int it = 0; it < 2; ++it) {
      int ci = it * 256 + tid;
      int row = ci >> 2, co = (ci & 3) * 8;
      gload_lds16(A + (size_t)(bm + row) * K + k0 + co, As + (it * 256 + wv * 64) * 8);
      gload_lds16(B + (size_t)(bn + row) * K + k0 + co, Bs + (it * 256 + wv * 64) * 8);
    }
    __syncthreads();

    short8 af[4], bfr[4];
#pragma unroll
    for (int im = 0; im < 4; ++im)
      af[im] = *reinterpret_cast<const short8*>(As + (wm + im * 16 + lr) * 32 + lq * 8);
#pragma unroll
    for (int jn = 0; jn < 4; ++jn)
      bfr[jn] = *reinterpret_cast<const short8*>(Bs + (wn + jn * 16 + lr) * 32 + lq * 8);
#pragma unroll
    for (int im = 0; im < 4; ++im)
#pragma unroll
      for (int jn = 0; jn < 4; ++jn)
        acc[im][jn] = MFMA16(af[im], bfr[jn], acc[im][jn]);
  }

#pragma unroll
  for (int im = 0; im < 4; ++im)
#pragma unroll
    for (int jn = 0; jn < 4; ++jn)
#pragma unroll
      for (int i = 0; i < 4; ++i) {
        int r = bm + wm + im * 16 + lq * 4 + i;
        int c = bn + wn + jn * 16 + lr;
        if (OUT_F32)
          reinterpret_cast<float*>(Cout)[(size_t)r * N + c] = acc[im][jn][i];
        else
          reinterpret_cast<bf16*>(Cout)[(size_t)r * N + c] = __float2bfloat16(acc[im][jn][i]);
      }
}

// ---------------- GEMM (128x64 tiles, f32 out): for GEMM2 occupancy -----------
__global__ __launch_bounds__(256, 2) void gemm_nt64(const bf16* __restrict__ A,
                                                    const bf16* __restrict__ B,
                                                    float* __restrict__ Cout,
                                                    int M, int N, int K) {
  __shared__ bf16 As[128 * 32];
  __shared__ bf16 Bs[64 * 32];
  const int tid = threadIdx.x;
  const int lane = tid & 63;
  const int wv = tid >> 6;
  const int lr = lane & 15, lq = lane >> 4;
  const int wm = (wv >> 1) * 64, wn = (wv & 1) * 32;

  const int nwgx = M >> 7;
  const int nwg = (M >> 7) * (N >> 6);
  const int id = blockIdx.x + gridDim.x * blockIdx.y;
  const int sid = (id & 7) * (nwg >> 3) + (id >> 3);   // XCD swizzle
  const int bm = (sid % nwgx) * 128, bn = (sid / nwgx) * 64;

  f32x4 acc[4][2] = {};

  for (int k0 = 0; k0 < K; k0 += 32) {
    __syncthreads();
#pragma unroll
    for (int it = 0; it < 2; ++it) {
      int ci = it * 256 + tid;            // A: 128 rows x 4 chunks = 512
      int row = ci >> 2, co = (ci & 3) * 8;
      gload_lds16(A + (size_t)(bm + row) * K + k0 + co, As + (it * 256 + wv * 64) * 8);
    }
    {
      int ci = tid;                       // B: 64 rows x 4 chunks = 256
      int row = ci >> 2, co = (ci & 3) * 8;
      gload_lds16(B + (size_t)(bn + row) * K + k0 + co, Bs + (wv * 64) * 8);
    }
    __syncthreads();

    short8 af[4], bfr[2];
#pragma unroll
    for (int im = 0; im < 4; ++im)
      af[im] = *reinterpret_cast<const short8*>(As + (wm + im * 16 + lr) * 32 + lq * 8);
#pragma unroll
    for (int jn = 0; jn < 2; ++jn)
      bfr[jn] = *reinterpret_cast<const short8*>(Bs + (wn + jn * 16 + lr) * 32 + lq * 8);
#pragma unroll
    for (int im = 0; im < 4; ++im)
#pragma unroll
      for (int jn = 0; jn < 2; ++jn)
        acc[im][jn] = MFMA16(af[im], bfr[jn], acc[im][jn]);
  }

#pragma unroll
  for (int im = 0; im < 4; ++im)
#pragma unroll
    for (int jn = 0; jn < 2; ++jn)
#pragma unroll
      for (int i = 0; i < 4; ++i) {
        int r = bm + wm + im * 16 + lq * 4 + i;
        int c = bn + wn + jn * 16 + lr;
        Cout[(size_t)r * N + c] = acc[im][jn][i];
      }
}

// ---------------- QK RMSNorm + RoPE (Q pre-scaled by 1/sqrt(Dh)) ---------------
__global__ void qk_norm_rope(const bf16* __restrict__ QKV,
                             const float* __restrict__ qw, const float* __restrict__ kw,
                             bf16* __restrict__ Qn, bf16* __restrict__ Kn) {
  const int lane = threadIdx.x & 63;
  const int w = threadIdx.x >> 6;
  const int row = blockIdx.x * 4 + w;
  const int s = row / 20;
  const int hh = row % 20;

  const bf16* src;
  bf16* dst;
  const float* wt;
  float outscale;
  if (hh < 16) {
    src = QKV + (size_t)s * NQKV + hh * Dh;
    dst = Qn + ((size_t)hh * S + s) * Dh;
    wt = qw;
    outscale = ATTN_SCALE;
  } else {
    int kvh = hh - 16;
    src = QKV + (size_t)s * NQKV + 2048 + kvh * Dh;
    dst = Kn + ((size_t)kvh * S + s) * Dh;
    wt = kw;
    outscale = 1.0f;
  }

  float x0 = __bfloat162float(src[lane]);
  float x1 = __bfloat162float(src[lane + 64]);
  float ss = x0 * x0 + x1 * x1;
#pragma unroll
  for (int off = 1; off < 64; off <<= 1) ss += __shfl_xor(ss, off);
  float rms = rsqrtf(ss * (1.0f / 128.0f) + 1e-6f);
  float n0 = x0 * rms * wt[lane];
  float n1 = x1 * rms * wt[lane + 64];

  float inv_freq = exp2f((float)lane * -0.2076205059304601f);
  float ang = (float)s * inv_freq;
  float sn, cs;
  sincosf(ang, &sn, &cs);
  float o0 = (n0 * cs - n1 * sn) * outscale;
  float o1 = (n1 * cs + n0 * sn) * outscale;
  dst[lane] = __float2bfloat16(o0);
  dst[lane + 64] = __float2bfloat16(o1);
}

// ---------------- V transpose: Vt[kvh][d][s] = QKV[s][2560 + kvh*128 + d] ------
__global__ void v_transpose(const bf16* __restrict__ QKV, bf16* __restrict__ Vt) {
  __shared__ bf16 t[64][65];
  const int s0 = blockIdx.x * 64;
  const int c0 = blockIdx.y * 64;
  const int kvh = c0 >> 7, d0 = c0 & 127;
#pragma unroll 4
  for (int i = 0; i < 16; ++i) {
    int lin = i * 256 + threadIdx.x;
    int r = lin >> 6, c = lin & 63;
    t[r][c] = QKV[(size_t)(s0 + r) * NQKV + 2560 + c0 + c];
  }
  __syncthreads();
#pragma unroll 4
  for (int i = 0; i < 16; ++i) {
    int lin = i * 256 + threadIdx.x;
    int d = lin >> 6, s = lin & 63;
    Vt[((size_t)kvh * 128 + d0 + d) * S + s0 + s] = t[s][d];
  }
}

// ---------------- chunk decode: u in [0,80) -> (qi, c, nc) ---------------------
__device__ __forceinline__ void chunk_decode(int u, int& qi, int& c, int& nc) {
  if (u < 8)       { qi = u;               c = 0;      nc = 1; }
  else if (u < 24) { int v = u - 8;  qi = 8  + (v >> 1); c = v & 1;  nc = 2; }
  else if (u < 48) { int v = u - 24; qi = 16 + v / 3;    c = v % 3;  nc = 3; }
  else             { int v = u - 48; qi = 24 + (v >> 2); c = v & 3;  nc = 4; }
}

// ---------------- causal GQA flash attention (v9) ------------------------------
// v8b swapped-softmax core; LDS cut 64->48 KB for 3 blocks/CU:
//  - K: async global_load_lds double-buffer (unchanged)
//  - V: SINGLE buffer, reg-staged (loadV during compute(t), writeV after the
//    bottom barrier) — v3's validated idiom; same chunk-swizzle convention,
//    PV reader unchanged. 2 barriers/tile.
__global__ __launch_bounds__(256, 2) void attn_fwd(const bf16* __restrict__ Qn,
                                                   const bf16* __restrict__ Kn,
                                                   const bf16* __restrict__ Vt,
                                                   bf16* __restrict__ AO,
                                                   bf16* __restrict__ Opart,
                                                   float* __restrict__ ml) {
  __shared__ bf16 Ks[2][64 * 128];   // 2 x 16 KB, chunk-swizzled
  __shared__ bf16 Vs[128 * 64];      // 16 KB, [d][k] chunk-swizzled

  const int tid = threadIdx.x;
  const int lane = tid & 63;
  const int w = tid >> 6;
  const int lr = lane & 15, lq = lane >> 4;

  const int bx = blockIdx.x;
  const int h = bx / 80, u = bx % 80;
  int qi, cch, nc;
  chunk_decode(u, qi, cch, nc);
  const int kvh = h >> 2;
  const int q0 = qi * 64;
  const int t0 = cch * 8;
  const int t1 = min(t0 + 8, qi + 1);

  const bf16* Qbase = Qn + ((size_t)h * S + q0 + w * 16) * Dh;
  const bf16* Kbase = Kn + (size_t)kvh * S * Dh;
  const bf16* Vbase = Vt + (size_t)kvh * Dh * S;

  short8 qf[4];
#pragma unroll
  for (int dd = 0; dd < 4; ++dd)
    qf[dd] = *reinterpret_cast<const short8*>(Qbase + (size_t)lr * Dh + dd * 32 + lq * 8);

  short8 ones;
#pragma unroll
  for (int e = 0; e < 8; ++e) ones[e] = (short)0x3F80;   // bf16 1.0

  float m = NEG_BIG;       // running max for q-row (w*16 + lr), shared by 4 lanes
  f32x4 lacc = {};
  f32x4 oacc[8] = {};
  float4 vreg[4];

  auto stageK = [&](int tile, int b) {
    const int kb = tile * 64;
#pragma unroll
    for (int i = 0; i < 4; ++i) {
      int chunk = i * 256 + tid;          // 16 chunks/row, 64 rows
      int r = chunk >> 4, c = chunk & 15;
      int cs = c ^ (r & 7);
      gload_lds16(Kbase + (size_t)(kb + r) * Dh + cs * 8,
                  (bf16*)Ks + b * 8192 + (i * 256 + w * 64) * 8);
    }
  };
  auto loadV = [&](int tile) {
    const int kb = tile * 64;
#pragma unroll
    for (int j = 0; j < 4; ++j) {
      int chunk = j * 256 + tid;          // 8 chunks/row, 128 rows
      int r = chunk >> 3, c = chunk & 7;
      vreg[j] = *reinterpret_cast<const float4*>(Vbase + (size_t)r * S + kb + c * 8);
    }
  };
  auto writeV = [&]() {
#pragma unroll
    for (int j = 0; j < 4; ++j) {
      int chunk = j * 256 + tid;
      int r = chunk >> 3, c = chunk & 7;
      int cs = c ^ (r & 7);
      *reinterpret_cast<float4*>((char*)Vs + r * 128 + cs * 16) = vreg[j];
    }
  };

  stageK(t0, 0);
  loadV(t0);
  __syncthreads();   // drain stageK(t0); vreg ready
  writeV();          // Vs <- V(t0)
  int buf = 0;

  for (int t = t0; t < t1; ++t) {
    __syncthreads();  // publish Vs(t); Ks[buf](t) already drained
    if (t + 1 < t1) { stageK(t + 1, buf ^ 1); loadV(t + 1); }  // async over compute

    // ---- QK^T (swapped): sacc[jn][i] = S[k = jn*16+lq*4+i][q = lr] ----
    f32x4 sacc[4] = {};
    __builtin_amdgcn_s_setprio(1);
#pragma unroll
    for (int jn = 0; jn < 4; ++jn) {
      int r = jn * 16 + lr;
      const char* kroww = (const char*)Ks + buf * 16384 + r * 256;
      int rx = r & 7;
#pragma unroll
      for (int dd = 0; dd < 4; ++dd) {
        int cg = (dd * 4 + lq) ^ rx;
        short8 kf = *reinterpret_cast<const short8*>(kroww + cg * 16);
        sacc[jn] = MFMA16(kf, qf[dd], sacc[jn]);   // A=K, B=Q
      }
    }
    __builtin_amdgcn_s_setprio(0);

    // ---- mask + per-lane row max (q-row = w*16 + lr) ----
    const bool diag = (t == qi);
    float p[4][4];
    float pm = NEG_BIG;
#pragma unroll
    for (int jn = 0; jn < 4; ++jn)
#pragma unroll
      for (int i = 0; i < 4; ++i) {
        float v = sacc[jn][i];
        if (diag && (jn * 16 + lq * 4 + i > w * 16 + lr)) v = NEG_BIG;
        p[jn][i] = v;
        pm = fmaxf(pm, v);
      }
    pm = fmaxf(pm, __shfl_xor(pm, 16));
    pm = fmaxf(pm, __shfl_xor(pm, 32));

    // defer-max rescale (wave-uniform branch)
    if (!__all(pm - m <= 8.0f)) {
      float mnew = fmaxf(m, pm);
      float a = __expf(m - mnew);
      m = mnew;
      float aq[4];
#pragma unroll
      for (int i = 0; i < 4; ++i) aq[i] = __shfl(a, lq * 4 + i);
#pragma unroll
      for (int i = 0; i < 4; ++i) {
        lacc[i] *= aq[i];
#pragma unroll
        for (int jd = 0; jd < 8; ++jd) oacc[jd][i] *= aq[i];
      }
    }

    // ---- exp + pack to bf16 pairs ----
    unsigned int wd[4][2];
#pragma unroll
    for (int jn = 0; jn < 4; ++jn)
#pragma unroll
      for (int uu = 0; uu < 2; ++uu) {
        float plo = __expf(p[jn][2 * uu] - m);
        float phi = __expf(p[jn][2 * uu + 1] - m);
        wd[jn][uu] = pack_bf16(plo, phi);
      }

    // ---- lane exchange: build PV A-frags pa[kk] ----
    short8 pa[2];
#pragma unroll
    for (int kk = 0; kk < 2; ++kk) {
      u32x4 w4;
#pragma unroll
      for (int tt = 0; tt < 4; ++tt) {
        int sl = lr + 16 * ((lq & 1) * 2 + (tt >> 1));
        unsigned int s0 = __shfl(wd[kk * 2][tt & 1], sl);
        unsigned int s1 = __shfl(wd[kk * 2 + 1][tt & 1], sl);
        w4[tt] = (lq >> 1) ? s1 : s0;
      }
      pa[kk] = __builtin_bit_cast(short8, w4);
    }

    // ---- O += P @ V; denominator via ones-MFMA ----
    __builtin_amdgcn_s_setprio(1);
#pragma unroll
    for (int kk = 0; kk < 2; ++kk) {
      lacc = MFMA16(pa[kk], ones, lacc);
#pragma unroll
      for (int jd = 0; jd < 8; ++jd) {
        int r = jd * 16 + lr;
        int cg = (kk * 4 + lq) ^ (r & 7);
        short8 vf = *reinterpret_cast<const short8*>((const char*)Vs + r * 128 + cg * 16);
        oacc[jd] = MFMA16(pa[kk], vf, oacc[jd]);
      }
    }
    __builtin_amdgcn_s_setprio(0);

    __syncthreads();  // Vs reads done block-wide; drains stageK(t+1)
    if (t + 1 < t1) writeV();
    buf ^= 1;
  }

  if (nc == 1) {
#pragma unroll
    for (int jd = 0; jd < 8; ++jd)
#pragma unroll
      for (int i = 0; i < 4; ++i) {
        float o = oacc[jd][i] / lacc[i];
        AO[(size_t)(q0 + w * 16 + lq * 4 + i) * E + h * Dh + jd * 16 + lr] = __float2bfloat16(o);
      }
  } else {
    const int pidx = h * 80 + u;
    bf16* Op = Opart + (size_t)pidx * 64 * 128;
#pragma unroll
    for (int jd = 0; jd < 8; ++jd)
#pragma unroll
      for (int i = 0; i < 4; ++i)
        Op[(w * 16 + lq * 4 + i) * 128 + jd * 16 + lr] = __float2bfloat16(oacc[jd][i]);
    if (lq == 0)
      ml[(size_t)pidx * 128 + (w * 16 + lr) * 2] = m;          // m for q-row lr
    if (lr == 0) {
#pragma unroll
      for (int i = 0; i < 4; ++i)
        ml[(size_t)pidx * 128 + (w * 16 + lq * 4 + i) * 2 + 1] = lacc[i];
    }
  }
}

// ---------------- combine partial chunks (qi >= 8) -----------------------------
__global__ __launch_bounds__(256) void attn_combine(const bf16* __restrict__ Opart,
                                                    const float* __restrict__ ml,
                                                    bf16* __restrict__ AO) {
  const int qi = 8 + blockIdx.x;
  const int h = blockIdx.y;
  const int nc = qi / 8 + 1;
  const int off = (qi < 16) ? 8 + (qi - 8) * 2
                : (qi < 24) ? 24 + (qi - 16) * 3
                            : 48 + (qi - 24) * 4;
  const int base = h * 80 + off;
  const int row = threadIdx.x >> 2;
  const int d0 = (threadIdx.x & 3) * 32;

  float mc[4], lc[4];
  float M = -INFINITY;
  for (int c = 0; c < nc; ++c) {
    mc[c] = ml[(size_t)(base + c) * 128 + row * 2];
    lc[c] = ml[(size_t)(base + c) * 128 + row * 2 + 1];
    M = fmaxf(M, mc[c]);
  }
  float L = 0.0f;
  float acc[32];
#pragma unroll
  for (int j = 0; j < 32; ++j) acc[j] = 0.0f;
  for (int c = 0; c < nc; ++c) {
    float wgt = __expf(mc[c] - M);
    L += wgt * lc[c];
    const short8* op = reinterpret_cast<const short8*>(
        Opart + (size_t)(base + c) * 8192 + row * 128 + d0);
#pragma unroll
    for (int j4 = 0; j4 < 4; ++j4) {
      short8 vv = op[j4];
#pragma unroll
      for (int e = 0; e < 8; ++e) {
        short sv = vv[e];
        acc[j4 * 8 + e] += wgt * __bfloat162float(*reinterpret_cast<bf16*>(&sv));
      }
    }
  }
  float inv = 1.0f / L;
  bf16* ao = AO + (size_t)(qi * 64 + row) * E + h * Dh + d0;
  short8 outv[4];
#pragma unroll
  for (int j4 = 0; j4 < 4; ++j4) {
#pragma unroll
    for (int e = 0; e < 8; ++e) outv[j4][e] = f2bs(acc[j4 * 8 + e] * inv);
    reinterpret_cast<short8*>(ao)[j4] = outv[j4];
  }
}

// ------------------------------------------------------------------------------
extern "C" void kernel_launch(void* const* d_in, const int* in_sizes, int n_in,
                              void* d_out, int out_size, void* d_ws, size_t ws_size,
                              hipStream_t stream) {
  const float* x  = (const float*)d_in[0];
  const float* Wq = (const float*)d_in[2];
  const float* Wk = (const float*)d_in[3];
  const float* Wv = (const float*)d_in[4];
  const float* Wo = (const float*)d_in[5];
  const float* qw = (const float*)d_in[6];
  const float* kw = (const float*)d_in[7];

  char* ws = (char*)d_ws;
  bf16* xb   = (bf16*)(ws + (0ull << 20));    // [2048][2048]   8 MB   (dead after GEMM1)
  bf16* Wcat = (bf16*)(ws + (8ull << 20));    // [3072][2048]  12 MB   (dead after GEMM1)
  bf16* Wob  = (bf16*)(ws + (20ull << 20));   // [2048][2048]   8 MB
  bf16* QKV  = (bf16*)(ws + (28ull << 20));   // [2048][3072]  12 MB   (dead after norm/transpose)
  bf16* Qn   = (bf16*)(ws + (40ull << 20));   // [16][2048][128] 8 MB
  bf16* Kn   = (bf16*)(ws + (48ull << 20));   // [4][2048][128]  2 MB
  bf16* Vt   = (bf16*)(ws + (50ull << 20));   // [4][128][2048]  2 MB
  bf16* AO   = (bf16*)(ws + (52ull << 20));   // [2048][2048]    8 MB
  bf16* Opart = (bf16*)(ws + (0ull << 20));   // 1280 x [64][128] = 20 MB, reuses xb+Wcat
  float* ml   = (float*)(ws + (28ull << 20)); // 1280 x 128 f32 = 640 KB, reuses QKV

  cvt_all<<<7168, 256, 0, stream>>>(x, Wq, Wk, Wv, Wo, xb, Wcat, Wob);

  gemm_nt<false><<<dim3(S / 128, NQKV / 128), 256, 0, stream>>>(xb, Wcat, QKV, S, NQKV, E);

  qk_norm_rope<<<(S * 20) / 4, 256, 0, stream>>>(QKV, qw, kw, Qn, Kn);
  v_transpose<<<dim3(S / 64, 512 / 64), 256, 0, stream>>>(QKV, Vt);

  attn_fwd<<<16 * 80, 256, 0, stream>>>(Qn, Kn, Vt, AO, Opart, ml);
  attn_combine<<<dim3(24, 16), 256, 0, stream>>>(Opart, ml, AO);

  gemm_nt64<<<dim3(S / 128, E / 64), 256, 0, stream>>>(AO, Wob, (float*)d_out, S, E, E);
}

// Round 14
// 167.874 us; speedup vs baseline: 1.0928x; 1.0928x over previous
//
#include <hip/hip_runtime.h>
#include <hip/hip_bf16.h>
#include <cstdint>
#include <cstddef>

using bf16 = __hip_bfloat16;
typedef __attribute__((ext_vector_type(8))) short short8;
typedef __attribute__((ext_vector_type(4))) float f32x4;
typedef __attribute__((ext_vector_type(4))) unsigned int u32x4;

#define MFMA16(a, b, c) __builtin_amdgcn_mfma_f32_16x16x32_bf16((a), (b), (c), 0, 0, 0)

static constexpr int S = 2048;
static constexpr int E = 2048;
static constexpr int H = 16;
static constexpr int KVH = 4;
static constexpr int Dh = 128;
static constexpr int NQKV = 3072;        // 2048 q + 512 k + 512 v
static constexpr float ATTN_SCALE = 0.08838834764831845f; // 1/sqrt(128)
static constexpr float NEG_BIG = -1e30f; // finite -inf surrogate

__device__ __forceinline__ short f2bs(float f) {
  __hip_bfloat16 h = __float2bfloat16(f);
  return *reinterpret_cast<short*>(&h);
}

// pack two floats to a bf16 pair (lo -> bits[15:0], hi -> bits[31:16]).
// (inline-asm v_cvt_pk_bf16_f32 produced NaN on gfx950 — round 11. Keep C++.)
__device__ __forceinline__ unsigned int pack_bf16(float lo, float hi) {
  return ((unsigned int)(unsigned short)f2bs(hi) << 16) |
         (unsigned int)(unsigned short)f2bs(lo);
}

__device__ __forceinline__ void gload_lds16(const void* g, void* l) {
  __builtin_amdgcn_global_load_lds(
      (const __attribute__((address_space(1))) unsigned int*)g,
      (__attribute__((address_space(3))) unsigned int*)l,
      16, 0, 0);
}

// ---------------- fused f32 -> bf16 convert for all 5 inputs -------------------
// segments (elems): x 4M | Wq 4M | Wk 1M | Wv 1M | Wo 4M  = 14M total
__global__ void cvt_all(const float* __restrict__ x,  const float* __restrict__ wq,
                        const float* __restrict__ wk, const float* __restrict__ wv,
                        const float* __restrict__ wo,
                        bf16* __restrict__ xb, bf16* __restrict__ wcat,
                        bf16* __restrict__ wob) {
  const long M1 = 4l << 20, M2 = 8l << 20, M3 = 9l << 20, M4 = 10l << 20, M5 = 14l << 20;
  long i = ((long)blockIdx.x * 256 + threadIdx.x) * 8;
  if (i >= M5) return;
  const float* src;
  bf16* dst;
  if (i < M1)      { src = x  + i;        dst = xb + i; }
  else if (i < M2) { src = wq + (i - M1); dst = wcat + (i - M1); }
  else if (i < M3) { src = wk + (i - M2); dst = wcat + 2048l * 2048 + (i - M2); }
  else if (i < M4) { src = wv + (i - M3); dst = wcat + 2560l * 2048 + (i - M3); }
  else             { src = wo + (i - M4); dst = wob + (i - M4); }
  const float4* s4 = reinterpret_cast<const float4*>(src);
  float4 a = s4[0];
  float4 b = s4[1];
  short8 o;
  o[0] = f2bs(a.x); o[1] = f2bs(a.y); o[2] = f2bs(a.z); o[3] = f2bs(a.w);
  o[4] = f2bs(b.x); o[5] = f2bs(b.y); o[6] = f2bs(b.z); o[7] = f2bs(b.w);
  *reinterpret_cast<short8*>(dst) = o;
}

// ---------------- GEMM (128x128): C[m][n] = sum_k A[m][k] * B[n][k] ------------
template <bool OUT_F32>
__global__ __launch_bounds__(256, 2) void gemm_nt(const bf16* __restrict__ A,
                                                  const bf16* __restrict__ B,
                                                  void* __restrict__ Cout,
                                                  int M, int N, int K) {
  __shared__ bf16 As[128 * 32];
  __shared__ bf16 Bs[128 * 32];
  const int tid = threadIdx.x;
  const int lane = tid & 63;
  const int wv = tid >> 6;
  const int lr = lane & 15, lq = lane >> 4;
  const int wm = (wv >> 1) * 64, wn = (wv & 1) * 64;

  const int nwgx = M >> 7;
  const int nwg = (M >> 7) * (N >> 7);
  const int id = blockIdx.x + gridDim.x * blockIdx.y;
  const int sid = (id & 7) * (nwg >> 3) + (id >> 3);   // XCD swizzle (bijective)
  const int bm = (sid % nwgx) * 128, bn = (sid / nwgx) * 128;

  f32x4 acc[4][4] = {};

  for (int k0 = 0; k0 < K; k0 += 32) {
    __syncthreads();
    for (int it = 0; it < 2; ++it) {
      int ci = it * 256 + tid;
      int row = ci >> 2, co = (ci & 3) * 8;
      gload_lds16(A + (size_t)(bm + row) * K + k0 + co, As + (it * 256 + wv * 64) * 8);
      gload_lds16(B + (size_t)(bn + row) * K + k0 + co, Bs + (it * 256 + wv * 64) * 8);
    }
    __syncthreads();

    short8 af[4], bfr[4];
#pragma unroll
    for (int im = 0; im < 4; ++im)
      af[im] = *reinterpret_cast<const short8*>(As + (wm + im * 16 + lr) * 32 + lq * 8);
#pragma unroll
    for (int jn = 0; jn < 4; ++jn)
      bfr[jn] = *reinterpret_cast<const short8*>(Bs + (wn + jn * 16 + lr) * 32 + lq * 8);
#pragma unroll
    for (int im = 0; im < 4; ++im)
#pragma unroll
      for (int jn = 0; jn < 4; ++jn)
        acc[im][jn] = MFMA16(af[im], bfr[jn], acc[im][jn]);
  }

#pragma unroll
  for (int im = 0; im < 4; ++im)
#pragma unroll
    for (int jn = 0; jn < 4; ++jn)
#pragma unroll
      for (int i = 0; i < 4; ++i) {
        int r = bm + wm + im * 16 + lq * 4 + i;
        int c = bn + wn + jn * 16 + lr;
        if (OUT_F32)
          reinterpret_cast<float*>(Cout)[(size_t)r * N + c] = acc[im][jn][i];
        else
          reinterpret_cast<bf16*>(Cout)[(size_t)r * N + c] = __float2bfloat16(acc[im][jn][i]);
      }
}

// ---------------- GEMM (128x64 tiles, f32 out): for GEMM2 occupancy -----------
__global__ __launch_bounds__(256, 2) void gemm_nt64(const bf16* __restrict__ A,
                                                    const bf16* __restrict__ B,
                                                    float* __restrict__ Cout,
                                                    int M, int N, int K) {
  __shared__ bf16 As[128 * 32];
  __shared__ bf16 Bs[64 * 32];
  const int tid = threadIdx.x;
  const int lane = tid & 63;
  const int wv = tid >> 6;
  const int lr = lane & 15, lq = lane >> 4;
  const int wm = (wv >> 1) * 64, wn = (wv & 1) * 32;

  const int nwgx = M >> 7;
  const int nwg = (M >> 7) * (N >> 6);
  const int id = blockIdx.x + gridDim.x * blockIdx.y;
  const int sid = (id & 7) * (nwg >> 3) + (id >> 3);   // XCD swizzle
  const int bm = (sid % nwgx) * 128, bn = (sid / nwgx) * 64;

  f32x4 acc[4][2] = {};

  for (int k0 = 0; k0 < K; k0 += 32) {
    __syncthreads();
#pragma unroll
    for (int it = 0; it < 2; ++it) {
      int ci = it * 256 + tid;            // A: 128 rows x 4 chunks = 512
      int row = ci >> 2, co = (ci & 3) * 8;
      gload_lds16(A + (size_t)(bm + row) * K + k0 + co, As + (it * 256 + wv * 64) * 8);
    }
    {
      int ci = tid;                       // B: 64 rows x 4 chunks = 256
      int row = ci >> 2, co = (ci & 3) * 8;
      gload_lds16(B + (size_t)(bn + row) * K + k0 + co, Bs + (wv * 64) * 8);
    }
    __syncthreads();

    short8 af[4], bfr[2];
#pragma unroll
    for (int im = 0; im < 4; ++im)
      af[im] = *reinterpret_cast<const short8*>(As + (wm + im * 16 + lr) * 32 + lq * 8);
#pragma unroll
    for (int jn = 0; jn < 2; ++jn)
      bfr[jn] = *reinterpret_cast<const short8*>(Bs + (wn + jn * 16 + lr) * 32 + lq * 8);
#pragma unroll
    for (int im = 0; im < 4; ++im)
#pragma unroll
      for (int jn = 0; jn < 2; ++jn)
        acc[im][jn] = MFMA16(af[im], bfr[jn], acc[im][jn]);
  }

#pragma unroll
  for (int im = 0; im < 4; ++im)
#pragma unroll
    for (int jn = 0; jn < 2; ++jn)
#pragma unroll
      for (int i = 0; i < 4; ++i) {
        int r = bm + wm + im * 16 + lq * 4 + i;
        int c = bn + wn + jn * 16 + lr;
        Cout[(size_t)r * N + c] = acc[im][jn][i];
      }
}

// ---------------- QK RMSNorm + RoPE (Q pre-scaled by 1/sqrt(Dh)) ---------------
__global__ void qk_norm_rope(const bf16* __restrict__ QKV,
                             const float* __restrict__ qw, const float* __restrict__ kw,
                             bf16* __restrict__ Qn, bf16* __restrict__ Kn) {
  const int lane = threadIdx.x & 63;
  const int w = threadIdx.x >> 6;
  const int row = blockIdx.x * 4 + w;
  const int s = row / 20;
  const int hh = row % 20;

  const bf16* src;
  bf16* dst;
  const float* wt;
  float outscale;
  if (hh < 16) {
    src = QKV + (size_t)s * NQKV + hh * Dh;
    dst = Qn + ((size_t)hh * S + s) * Dh;
    wt = qw;
    outscale = ATTN_SCALE;
  } else {
    int kvh = hh - 16;
    src = QKV + (size_t)s * NQKV + 2048 + kvh * Dh;
    dst = Kn + ((size_t)kvh * S + s) * Dh;
    wt = kw;
    outscale = 1.0f;
  }

  float x0 = __bfloat162float(src[lane]);
  float x1 = __bfloat162float(src[lane + 64]);
  float ss = x0 * x0 + x1 * x1;
#pragma unroll
  for (int off = 1; off < 64; off <<= 1) ss += __shfl_xor(ss, off);
  float rms = rsqrtf(ss * (1.0f / 128.0f) + 1e-6f);
  float n0 = x0 * rms * wt[lane];
  float n1 = x1 * rms * wt[lane + 64];

  float inv_freq = exp2f((float)lane * -0.2076205059304601f);
  float ang = (float)s * inv_freq;
  float sn, cs;
  sincosf(ang, &sn, &cs);
  float o0 = (n0 * cs - n1 * sn) * outscale;
  float o1 = (n1 * cs + n0 * sn) * outscale;
  dst[lane] = __float2bfloat16(o0);
  dst[lane + 64] = __float2bfloat16(o1);
}

// ---------------- V transpose: Vt[kvh][d][s] = QKV[s][2560 + kvh*128 + d] ------
__global__ void v_transpose(const bf16* __restrict__ QKV, bf16* __restrict__ Vt) {
  __shared__ bf16 t[64][65];
  const int s0 = blockIdx.x * 64;
  const int c0 = blockIdx.y * 64;
  const int kvh = c0 >> 7, d0 = c0 & 127;
#pragma unroll 4
  for (int i = 0; i < 16; ++i) {
    int lin = i * 256 + threadIdx.x;
    int r = lin >> 6, c = lin & 63;
    t[r][c] = QKV[(size_t)(s0 + r) * NQKV + 2560 + c0 + c];
  }
  __syncthreads();
#pragma unroll 4
  for (int i = 0; i < 16; ++i) {
    int lin = i * 256 + threadIdx.x;
    int d = lin >> 6, s = lin & 63;
    Vt[((size_t)kvh * 128 + d0 + d) * S + s0 + s] = t[s][d];
  }
}

// ---------------- chunk decode: u in [0,80) -> (qi, c, nc) ---------------------
__device__ __forceinline__ void chunk_decode(int u, int& qi, int& c, int& nc) {
  if (u < 8)       { qi = u;               c = 0;      nc = 1; }
  else if (u < 24) { int v = u - 8;  qi = 8  + (v >> 1); c = v & 1;  nc = 2; }
  else if (u < 48) { int v = u - 24; qi = 16 + v / 3;    c = v % 3;  nc = 3; }
  else             { int v = u - 48; qi = 24 + (v >> 2); c = v & 3;  nc = 4; }
}

// ---------------- causal GQA flash attention (v8b — validated 63.5 us) ---------
// Swapped QK^T register softmax; K+V async global_load_lds double-buffer,
// ONE __syncthreads per tile; ones-MFMA denominator. 88 VGPR, no spill.
// LDS = 2x16K (K) + 2x16K (V) = 64 KB -> 2 blocks/CU.
// DO NOT: reg-stage V (round 13: spilled, 70 MB scratch writes, 63->81 us);
//         raise launch_bounds (round 6); V direct-L2 (rounds 5/7).
__global__ __launch_bounds__(256, 2) void attn_fwd(const bf16* __restrict__ Qn,
                                                   const bf16* __restrict__ Kn,
                                                   const bf16* __restrict__ Vt,
                                                   bf16* __restrict__ AO,
                                                   bf16* __restrict__ Opart,
                                                   float* __restrict__ ml) {
  __shared__ bf16 Ks[2][64 * 128];   // 2 x 16 KB, chunk-swizzled
  __shared__ bf16 Vs[2][128 * 64];   // 2 x 16 KB, [d][k] chunk-swizzled

  const int tid = threadIdx.x;
  const int lane = tid & 63;
  const int w = tid >> 6;
  const int lr = lane & 15, lq = lane >> 4;

  const int bx = blockIdx.x;
  const int h = bx / 80, u = bx % 80;
  int qi, cch, nc;
  chunk_decode(u, qi, cch, nc);
  const int kvh = h >> 2;
  const int q0 = qi * 64;
  const int t0 = cch * 8;
  const int t1 = min(t0 + 8, qi + 1);

  const bf16* Qbase = Qn + ((size_t)h * S + q0 + w * 16) * Dh;
  const bf16* Kbase = Kn + (size_t)kvh * S * Dh;
  const bf16* Vbase = Vt + (size_t)kvh * Dh * S;

  short8 qf[4];
#pragma unroll
  for (int dd = 0; dd < 4; ++dd)
    qf[dd] = *reinterpret_cast<const short8*>(Qbase + (size_t)lr * Dh + dd * 32 + lq * 8);

  short8 ones;
#pragma unroll
  for (int e = 0; e < 8; ++e) ones[e] = (short)0x3F80;   // bf16 1.0

  float m = NEG_BIG;       // running max for q-row (w*16 + lr), shared by 4 lanes
  f32x4 lacc = {};
  f32x4 oacc[8] = {};

  auto stageK = [&](int tile, int b) {
    const int kb = tile * 64;
#pragma unroll
    for (int i = 0; i < 4; ++i) {
      int chunk = i * 256 + tid;          // 16 chunks/row, 64 rows
      int r = chunk >> 4, c = chunk & 15;
      int cs = c ^ (r & 7);
      gload_lds16(Kbase + (size_t)(kb + r) * Dh + cs * 8,
                  (bf16*)Ks + b * 8192 + (i * 256 + w * 64) * 8);
    }
  };
  auto stageV = [&](int tile, int b) {
    const int kb = tile * 64;
#pragma unroll
    for (int i = 0; i < 4; ++i) {
      int chunk = i * 256 + tid;          // 8 chunks/row, 128 rows
      int r = chunk >> 3, c = chunk & 7;
      int cs = c ^ (r & 7);
      gload_lds16(Vbase + (size_t)r * S + kb + cs * 8,
                  (bf16*)Vs + b * 8192 + (i * 256 + w * 64) * 8);
    }
  };

  stageK(t0, 0);
  stageV(t0, 0);
  __syncthreads();   // drain stage(t0)
  int buf = 0;

  for (int t = t0; t < t1; ++t) {
    if (t + 1 < t1) { stageK(t + 1, buf ^ 1); stageV(t + 1, buf ^ 1); }  // async

    // ---- QK^T (swapped): sacc[jn][i] = S[k = jn*16+lq*4+i][q = lr] ----
    f32x4 sacc[4] = {};
    __builtin_amdgcn_s_setprio(1);
#pragma unroll
    for (int jn = 0; jn < 4; ++jn) {
      int r = jn * 16 + lr;
      const char* kroww = (const char*)Ks + buf * 16384 + r * 256;
      int rx = r & 7;
#pragma unroll
      for (int dd = 0; dd < 4; ++dd) {
        int cg = (dd * 4 + lq) ^ rx;
        short8 kf = *reinterpret_cast<const short8*>(kroww + cg * 16);
        sacc[jn] = MFMA16(kf, qf[dd], sacc[jn]);   // A=K, B=Q
      }
    }
    __builtin_amdgcn_s_setprio(0);

    // ---- mask + per-lane row max (q-row = w*16 + lr) ----
    const bool diag = (t == qi);
    float p[4][4];
    float pm = NEG_BIG;
#pragma unroll
    for (int jn = 0; jn < 4; ++jn)
#pragma unroll
      for (int i = 0; i < 4; ++i) {
        float v = sacc[jn][i];
        if (diag && (jn * 16 + lq * 4 + i > w * 16 + lr)) v = NEG_BIG;
        p[jn][i] = v;
        pm = fmaxf(pm, v);
      }
    pm = fmaxf(pm, __shfl_xor(pm, 16));
    pm = fmaxf(pm, __shfl_xor(pm, 32));

    // defer-max rescale (wave-uniform branch)
    if (!__all(pm - m <= 8.0f)) {
      float mnew = fmaxf(m, pm);
      float a = __expf(m - mnew);
      m = mnew;
      float aq[4];
#pragma unroll
      for (int i = 0; i < 4; ++i) aq[i] = __shfl(a, lq * 4 + i);
#pragma unroll
      for (int i = 0; i < 4; ++i) {
        lacc[i] *= aq[i];
#pragma unroll
        for (int jd = 0; jd < 8; ++jd) oacc[jd][i] *= aq[i];
      }
    }

    // ---- exp + pack to bf16 pairs ----
    unsigned int wd[4][2];
#pragma unroll
    for (int jn = 0; jn < 4; ++jn)
#pragma unroll
      for (int uu = 0; uu < 2; ++uu) {
        float plo = __expf(p[jn][2 * uu] - m);
        float phi = __expf(p[jn][2 * uu + 1] - m);
        wd[jn][uu] = pack_bf16(plo, phi);
      }

    // ---- lane exchange: build PV A-frags pa[kk] ----
    short8 pa[2];
#pragma unroll
    for (int kk = 0; kk < 2; ++kk) {
      u32x4 w4;
#pragma unroll
      for (int tt = 0; tt < 4; ++tt) {
        int sl = lr + 16 * ((lq & 1) * 2 + (tt >> 1));
        unsigned int s0 = __shfl(wd[kk * 2][tt & 1], sl);
        unsigned int s1 = __shfl(wd[kk * 2 + 1][tt & 1], sl);
        w4[tt] = (lq >> 1) ? s1 : s0;
      }
      pa[kk] = __builtin_bit_cast(short8, w4);
    }

    // ---- O += P @ V; denominator via ones-MFMA ----
    __builtin_amdgcn_s_setprio(1);
#pragma unroll
    for (int kk = 0; kk < 2; ++kk) {
      lacc = MFMA16(pa[kk], ones, lacc);
#pragma unroll
      for (int jd = 0; jd < 8; ++jd) {
        int r = jd * 16 + lr;
        int cg = (kk * 4 + lq) ^ (r & 7);
        short8 vf = *reinterpret_cast<const short8*>((const char*)Vs + buf * 16384 + r * 128 + cg * 16);
        oacc[jd] = MFMA16(pa[kk], vf, oacc[jd]);
      }
    }
    __builtin_amdgcn_s_setprio(0);

    __syncthreads();  // drains stage(t+1) into buf^1; all reads of buf done
    buf ^= 1;
  }

  if (nc == 1) {
#pragma unroll
    for (int jd = 0; jd < 8; ++jd)
#pragma unroll
      for (int i = 0; i < 4; ++i) {
        float o = oacc[jd][i] / lacc[i];
        AO[(size_t)(q0 + w * 16 + lq * 4 + i) * E + h * Dh + jd * 16 + lr] = __float2bfloat16(o);
      }
  } else {
    const int pidx = h * 80 + u;
    bf16* Op = Opart + (size_t)pidx * 64 * 128;
#pragma unroll
    for (int jd = 0; jd < 8; ++jd)
#pragma unroll
      for (int i = 0; i < 4; ++i)
        Op[(w * 16 + lq * 4 + i) * 128 + jd * 16 + lr] = __float2bfloat16(oacc[jd][i]);
    if (lq == 0)
      ml[(size_t)pidx * 128 + (w * 16 + lr) * 2] = m;          // m for q-row lr
    if (lr == 0) {
#pragma unroll
      for (int i = 0; i < 4; ++i)
        ml[(size_t)pidx * 128 + (w * 16 + lq * 4 + i) * 2 + 1] = lacc[i];
    }
  }
}

// ---------------- combine partial chunks (qi >= 8) -----------------------------
__global__ __launch_bounds__(256) void attn_combine(const bf16* __restrict__ Opart,
                                                    const float* __restrict__ ml,
                                                    bf16* __restrict__ AO) {
  const int qi = 8 + blockIdx.x;
  const int h = blockIdx.y;
  const int nc = qi / 8 + 1;
  const int off = (qi < 16) ? 8 + (qi - 8) * 2
                : (qi < 24) ? 24 + (qi - 16) * 3
                            : 48 + (qi - 24) * 4;
  const int base = h * 80 + off;
  const int row = threadIdx.x >> 2;
  const int d0 = (threadIdx.x & 3) * 32;

  float mc[4], lc[4];
  float M = -INFINITY;
  for (int c = 0; c < nc; ++c) {
    mc[c] = ml[(size_t)(base + c) * 128 + row * 2];
    lc[c] = ml[(size_t)(base + c) * 128 + row * 2 + 1];
    M = fmaxf(M, mc[c]);
  }
  float L = 0.0f;
  float acc[32];
#pragma unroll
  for (int j = 0; j < 32; ++j) acc[j] = 0.0f;
  for (int c = 0; c < nc; ++c) {
    float wgt = __expf(mc[c] - M);
    L += wgt * lc[c];
    const short8* op = reinterpret_cast<const short8*>(
        Opart + (size_t)(base + c) * 8192 + row * 128 + d0);
#pragma unroll
    for (int j4 = 0; j4 < 4; ++j4) {
      short8 vv = op[j4];
#pragma unroll
      for (int e = 0; e < 8; ++e) {
        short sv = vv[e];
        acc[j4 * 8 + e] += wgt * __bfloat162float(*reinterpret_cast<bf16*>(&sv));
      }
    }
  }
  float inv = 1.0f / L;
  bf16* ao = AO + (size_t)(qi * 64 + row) * E + h * Dh + d0;
  short8 outv[4];
#pragma unroll
  for (int j4 = 0; j4 < 4; ++j4) {
#pragma unroll
    for (int e = 0; e < 8; ++e) outv[j4][e] = f2bs(acc[j4 * 8 + e] * inv);
    reinterpret_cast<short8*>(ao)[j4] = outv[j4];
  }
}

// ------------------------------------------------------------------------------
extern "C" void kernel_launch(void* const* d_in, const int* in_sizes, int n_in,
                              void* d_out, int out_size, void* d_ws, size_t ws_size,
                              hipStream_t stream) {
  const float* x  = (const float*)d_in[0];
  const float* Wq = (const float*)d_in[2];
  const float* Wk = (const float*)d_in[3];
  const float* Wv = (const float*)d_in[4];
  const float* Wo = (const float*)d_in[5];
  const float* qw = (const float*)d_in[6];
  const float* kw = (const float*)d_in[7];

  char* ws = (char*)d_ws;
  bf16* xb   = (bf16*)(ws + (0ull << 20));    // [2048][2048]   8 MB   (dead after GEMM1)
  bf16* Wcat = (bf16*)(ws + (8ull << 20));    // [3072][2048]  12 MB   (dead after GEMM1)
  bf16* Wob  = (bf16*)(ws + (20ull << 20));   // [2048][2048]   8 MB
  bf16* QKV  = (bf16*)(ws + (28ull << 20));   // [2048][3072]  12 MB   (dead after norm/transpose)
  bf16* Qn   = (bf16*)(ws + (40ull << 20));   // [16][2048][128] 8 MB
  bf16* Kn   = (bf16*)(ws + (48ull << 20));   // [4][2048][128]  2 MB
  bf16* Vt   = (bf16*)(ws + (50ull << 20));   // [4][128][2048]  2 MB
  bf16* AO   = (bf16*)(ws + (52ull << 20));   // [2048][2048]    8 MB
  bf16* Opart = (bf16*)(ws + (0ull << 20));   // 1280 x [64][128] = 20 MB, reuses xb+Wcat
  float* ml   = (float*)(ws + (28ull << 20)); // 1280 x 128 f32 = 640 KB, reuses QKV

  cvt_all<<<7168, 256, 0, stream>>>(x, Wq, Wk, Wv, Wo, xb, Wcat, Wob);

  gemm_nt<false><<<dim3(S / 128, NQKV / 128), 256, 0, stream>>>(xb, Wcat, QKV, S, NQKV, E);

  qk_norm_rope<<<(S * 20) / 4, 256, 0, stream>>>(QKV, qw, kw, Qn, Kn);
  v_transpose<<<dim3(S / 64, 512 / 64), 256, 0, stream>>>(QKV, Vt);

  attn_fwd<<<16 * 80, 256, 0, stream>>>(Qn, Kn, Vt, AO, Opart, ml);
  attn_combine<<<dim3(24, 16), 256, 0, stream>>>(Opart, ml, AO);

  gemm_nt64<<<dim3(S / 128, E / 64), 256, 0, stream>>>(AO, Wob, (float*)d_out, S, E, E);
}

// Round 15
// 160.914 us; speedup vs baseline: 1.1401x; 1.0433x over previous
//
#include <hip/hip_runtime.h>
#include <hip/hip_bf16.h>
#include <cstdint>
#include <cstddef>

using bf16 = __hip_bfloat16;
typedef __attribute__((ext_vector_type(8))) short short8;
typedef __attribute__((ext_vector_type(4))) float f32x4;

#define MFMA16(a, b, c) __builtin_amdgcn_mfma_f32_16x16x32_bf16((a), (b), (c), 0, 0, 0)

static constexpr int S = 2048;
static constexpr int E = 2048;
static constexpr int H = 16;
static constexpr int KVH = 4;
static constexpr int Dh = 128;
static constexpr int NQKV = 3072;        // 2048 q + 512 k + 512 v
static constexpr float ATTN_SCALE = 0.08838834764831845f; // 1/sqrt(128)
static constexpr float NEG_BIG = -1e30f; // finite -inf surrogate

__device__ __forceinline__ short f2bs(float f) {
  __hip_bfloat16 h = __float2bfloat16(f);
  return *reinterpret_cast<short*>(&h);
}

// pack two floats to a bf16 pair (lo -> bits[15:0], hi -> bits[31:16]).
// (inline-asm v_cvt_pk_bf16_f32 produced NaN on gfx950 — round 11. Keep C++.)
__device__ __forceinline__ unsigned int pack_bf16(float lo, float hi) {
  return ((unsigned int)(unsigned short)f2bs(hi) << 16) |
         (unsigned int)(unsigned short)f2bs(lo);
}

__device__ __forceinline__ void gload_lds16(const void* g, void* l) {
  __builtin_amdgcn_global_load_lds(
      (const __attribute__((address_space(1))) unsigned int*)g,
      (__attribute__((address_space(3))) unsigned int*)l,
      16, 0, 0);
}

// ---------------- fused f32 -> bf16 convert for all 5 inputs -------------------
// segments (elems): x 4M | Wq 4M | Wk 1M | Wv 1M | Wo 4M  = 14M total
__global__ void cvt_all(const float* __restrict__ x,  const float* __restrict__ wq,
                        const float* __restrict__ wk, const float* __restrict__ wv,
                        const float* __restrict__ wo,
                        bf16* __restrict__ xb, bf16* __restrict__ wcat,
                        bf16* __restrict__ wob) {
  const long M1 = 4l << 20, M2 = 8l << 20, M3 = 9l << 20, M4 = 10l << 20, M5 = 14l << 20;
  long i = ((long)blockIdx.x * 256 + threadIdx.x) * 8;
  if (i >= M5) return;
  const float* src;
  bf16* dst;
  if (i < M1)      { src = x  + i;        dst = xb + i; }
  else if (i < M2) { src = wq + (i - M1); dst = wcat + (i - M1); }
  else if (i < M3) { src = wk + (i - M2); dst = wcat + 2048l * 2048 + (i - M2); }
  else if (i < M4) { src = wv + (i - M3); dst = wcat + 2560l * 2048 + (i - M3); }
  else             { src = wo + (i - M4); dst = wob + (i - M4); }
  const float4* s4 = reinterpret_cast<const float4*>(src);
  float4 a = s4[0];
  float4 b = s4[1];
  short8 o;
  o[0] = f2bs(a.x); o[1] = f2bs(a.y); o[2] = f2bs(a.z); o[3] = f2bs(a.w);
  o[4] = f2bs(b.x); o[5] = f2bs(b.y); o[6] = f2bs(b.z); o[7] = f2bs(b.w);
  *reinterpret_cast<short8*>(dst) = o;
}

// ---------------- GEMM (128x128): C[m][n] = sum_k A[m][k] * B[n][k] ------------
template <bool OUT_F32>
__global__ __launch_bounds__(256, 2) void gemm_nt(const bf16* __restrict__ A,
                                                  const bf16* __restrict__ B,
                                                  void* __restrict__ Cout,
                                                  int M, int N, int K) {
  __shared__ bf16 As[128 * 32];
  __shared__ bf16 Bs[128 * 32];
  const int tid = threadIdx.x;
  const int lane = tid & 63;
  const int wv = tid >> 6;
  const int lr = lane & 15, lq = lane >> 4;
  const int wm = (wv >> 1) * 64, wn = (wv & 1) * 64;

  const int nwgx = M >> 7;
  const int nwg = (M >> 7) * (N >> 7);
  const int id = blockIdx.x + gridDim.x * blockIdx.y;
  const int sid = (id & 7) * (nwg >> 3) + (id >> 3);   // XCD swizzle (bijective)
  const int bm = (sid % nwgx) * 128, bn = (sid / nwgx) * 128;

  f32x4 acc[4][4] = {};

  for (int k0 = 0; k0 < K; k0 += 32) {
    __syncthreads();
    for (int it = 0; it < 2; ++it) {
      int ci = it * 256 + tid;
      int row = ci >> 2, co = (ci & 3) * 8;
      gload_lds16(A + (size_t)(bm + row) * K + k0 + co, As + (it * 256 + wv * 64) * 8);
      gload_lds16(B + (size_t)(bn + row) * K + k0 + co, Bs + (it * 256 + wv * 64) * 8);
    }
    __syncthreads();

    short8 af[4], bfr[4];
#pragma unroll
    for (int im = 0; im < 4; ++im)
      af[im] = *reinterpret_cast<const short8*>(As + (wm + im * 16 + lr) * 32 + lq * 8);
#pragma unroll
    for (int jn = 0; jn < 4; ++jn)
      bfr[jn] = *reinterpret_cast<const short8*>(Bs + (wn + jn * 16 + lr) * 32 + lq * 8);
#pragma unroll
    for (int im = 0; im < 4; ++im)
#pragma unroll
      for (int jn = 0; jn < 4; ++jn)
        acc[im][jn] = MFMA16(af[im], bfr[jn], acc[im][jn]);
  }

#pragma unroll
  for (int im = 0; im < 4; ++im)
#pragma unroll
    for (int jn = 0; jn < 4; ++jn)
#pragma unroll
      for (int i = 0; i < 4; ++i) {
        int r = bm + wm + im * 16 + lq * 4 + i;
        int c = bn + wn + jn * 16 + lr;
        if (OUT_F32)
          reinterpret_cast<float*>(Cout)[(size_t)r * N + c] = acc[im][jn][i];
        else
          reinterpret_cast<bf16*>(Cout)[(size_t)r * N + c] = __float2bfloat16(acc[im][jn][i]);
      }
}

// ---------------- GEMM (128x64 tiles, f32 out): for GEMM2 occupancy -----------
__global__ __launch_bounds__(256, 2) void gemm_nt64(const bf16* __restrict__ A,
                                                    const bf16* __restrict__ B,
                                                    float* __restrict__ Cout,
                                                    int M, int N, int K) {
  __shared__ bf16 As[128 * 32];
  __shared__ bf16 Bs[64 * 32];
  const int tid = threadIdx.x;
  const int lane = tid & 63;
  const int wv = tid >> 6;
  const int lr = lane & 15, lq = lane >> 4;
  const int wm = (wv >> 1) * 64, wn = (wv & 1) * 32;

  const int nwgx = M >> 7;
  const int nwg = (M >> 7) * (N >> 6);
  const int id = blockIdx.x + gridDim.x * blockIdx.y;
  const int sid = (id & 7) * (nwg >> 3) + (id >> 3);   // XCD swizzle
  const int bm = (sid % nwgx) * 128, bn = (sid / nwgx) * 64;

  f32x4 acc[4][2] = {};

  for (int k0 = 0; k0 < K; k0 += 32) {
    __syncthreads();
#pragma unroll
    for (int it = 0; it < 2; ++it) {
      int ci = it * 256 + tid;            // A: 128 rows x 4 chunks = 512
      int row = ci >> 2, co = (ci & 3) * 8;
      gload_lds16(A + (size_t)(bm + row) * K + k0 + co, As + (it * 256 + wv * 64) * 8);
    }
    {
      int ci = tid;                       // B: 64 rows x 4 chunks = 256
      int row = ci >> 2, co = (ci & 3) * 8;
      gload_lds16(B + (size_t)(bn + row) * K + k0 + co, Bs + (wv * 64) * 8);
    }
    __syncthreads();

    short8 af[4], bfr[2];
#pragma unroll
    for (int im = 0; im < 4; ++im)
      af[im] = *reinterpret_cast<const short8*>(As + (wm + im * 16 + lr) * 32 + lq * 8);
#pragma unroll
    for (int jn = 0; jn < 2; ++jn)
      bfr[jn] = *reinterpret_cast<const short8*>(Bs + (wn + jn * 16 + lr) * 32 + lq * 8);
#pragma unroll
    for (int im = 0; im < 4; ++im)
#pragma unroll
      for (int jn = 0; jn < 2; ++jn)
        acc[im][jn] = MFMA16(af[im], bfr[jn], acc[im][jn]);
  }

#pragma unroll
  for (int im = 0; im < 4; ++im)
#pragma unroll
    for (int jn = 0; jn < 2; ++jn)
#pragma unroll
      for (int i = 0; i < 4; ++i) {
        int r = bm + wm + im * 16 + lq * 4 + i;
        int c = bn + wn + jn * 16 + lr;
        Cout[(size_t)r * N + c] = acc[im][jn][i];
      }
}

// ---------------- fused QK RMSNorm+RoPE  +  V transpose ------------------------
// blocks [0,10240): norm/rope rows; blocks [10240,10496): V transpose tiles.
__global__ void qk_norm_rope_vt(const bf16* __restrict__ QKV,
                                const float* __restrict__ qw, const float* __restrict__ kw,
                                bf16* __restrict__ Qn, bf16* __restrict__ Kn,
                                bf16* __restrict__ Vt) {
  __shared__ bf16 t[64][65];
  if (blockIdx.x >= 10240) {
    const int vb = blockIdx.x - 10240;
    const int s0 = (vb & 31) * 64;
    const int c0 = (vb >> 5) * 64;
    const int kvh = c0 >> 7, d0 = c0 & 127;
#pragma unroll 4
    for (int i = 0; i < 16; ++i) {
      int lin = i * 256 + threadIdx.x;
      int r = lin >> 6, c = lin & 63;
      t[r][c] = QKV[(size_t)(s0 + r) * NQKV + 2560 + c0 + c];
    }
    __syncthreads();
#pragma unroll 4
    for (int i = 0; i < 16; ++i) {
      int lin = i * 256 + threadIdx.x;
      int d = lin >> 6, s = lin & 63;
      Vt[((size_t)kvh * 128 + d0 + d) * S + s0 + s] = t[s][d];
    }
    return;
  }

  const int lane = threadIdx.x & 63;
  const int w = threadIdx.x >> 6;
  const int row = blockIdx.x * 4 + w;
  const int s = row / 20;
  const int hh = row % 20;

  const bf16* src;
  bf16* dst;
  const float* wt;
  float outscale;
  if (hh < 16) {
    src = QKV + (size_t)s * NQKV + hh * Dh;
    dst = Qn + ((size_t)hh * S + s) * Dh;
    wt = qw;
    outscale = ATTN_SCALE;
  } else {
    int kvh = hh - 16;
    src = QKV + (size_t)s * NQKV + 2048 + kvh * Dh;
    dst = Kn + ((size_t)kvh * S + s) * Dh;
    wt = kw;
    outscale = 1.0f;
  }

  float x0 = __bfloat162float(src[lane]);
  float x1 = __bfloat162float(src[lane + 64]);
  float ss = x0 * x0 + x1 * x1;
#pragma unroll
  for (int off = 1; off < 64; off <<= 1) ss += __shfl_xor(ss, off);
  float rms = rsqrtf(ss * (1.0f / 128.0f) + 1e-6f);
  float n0 = x0 * rms * wt[lane];
  float n1 = x1 * rms * wt[lane + 64];

  float inv_freq = exp2f((float)lane * -0.2076205059304601f);
  float ang = (float)s * inv_freq;
  float sn, cs;
  sincosf(ang, &sn, &cs);
  float o0 = (n0 * cs - n1 * sn) * outscale;
  float o1 = (n1 * cs + n0 * sn) * outscale;
  dst[lane] = __float2bfloat16(o0);
  dst[lane + 64] = __float2bfloat16(o1);
}

// ---------------- chunk decode: u in [0,80) -> (qi, c, nc) ---------------------
__device__ __forceinline__ void chunk_decode(int u, int& qi, int& c, int& nc) {
  if (u < 8)       { qi = u;               c = 0;      nc = 1; }
  else if (u < 24) { int v = u - 8;  qi = 8  + (v >> 1); c = v & 1;  nc = 2; }
  else if (u < 48) { int v = u - 24; qi = 16 + v / 3;    c = v % 3;  nc = 3; }
  else             { int v = u - 48; qi = 24 + (v >> 2); c = v & 3;  nc = 4; }
}

// ---------------- causal GQA flash attention (v10) -----------------------------
// v8b core (swapped QK^T register softmax, K+V async dbuf, 1 barrier/tile,
// ones-MFMA denominator) with the P lane-exchange moved from 16 __shfl to a
// per-wave swizzled LDS round-trip: 4x ds_write_b64 + 2x ds_read_b128.
// Slot-XOR swizzle (slot ^= lr&7): stores ~2-way, reads aggregate-uniform.
// LDS = 2x16K (K) + 2x16K (V) + 8K (P) = 72 KB -> 2 blocks/CU.
// DO NOT: reg-stage V (round 13 spill); raise launch_bounds (round 6);
//         V direct-L2 (rounds 5/7); inline-asm cvt_pk (round 11 NaN).
__global__ __launch_bounds__(256, 2) void attn_fwd(const bf16* __restrict__ Qn,
                                                   const bf16* __restrict__ Kn,
                                                   const bf16* __restrict__ Vt,
                                                   bf16* __restrict__ AO,
                                                   bf16* __restrict__ Opart,
                                                   float* __restrict__ ml) {
  __shared__ bf16 Ks[2][64 * 128];   // 2 x 16 KB, chunk-swizzled
  __shared__ bf16 Vs[2][128 * 64];   // 2 x 16 KB, [d][k] chunk-swizzled
  __shared__ bf16 Ps[4][16 * 64];    // per-wave P, slot-XOR swizzled, 2 KB each

  const int tid = threadIdx.x;
  const int lane = tid & 63;
  const int w = tid >> 6;
  const int lr = lane & 15, lq = lane >> 4;

  const int bx = blockIdx.x;
  const int h = bx / 80, u = bx % 80;
  int qi, cch, nc;
  chunk_decode(u, qi, cch, nc);
  const int kvh = h >> 2;
  const int q0 = qi * 64;
  const int t0 = cch * 8;
  const int t1 = min(t0 + 8, qi + 1);

  const bf16* Qbase = Qn + ((size_t)h * S + q0 + w * 16) * Dh;
  const bf16* Kbase = Kn + (size_t)kvh * S * Dh;
  const bf16* Vbase = Vt + (size_t)kvh * Dh * S;
  char* Pw = (char*)&Ps[w][0];

  short8 qf[4];
#pragma unroll
  for (int dd = 0; dd < 4; ++dd)
    qf[dd] = *reinterpret_cast<const short8*>(Qbase + (size_t)lr * Dh + dd * 32 + lq * 8);

  short8 ones;
#pragma unroll
  for (int e = 0; e < 8; ++e) ones[e] = (short)0x3F80;   // bf16 1.0

  float m = NEG_BIG;       // running max for q-row (w*16 + lr), shared by 4 lanes
  f32x4 lacc = {};
  f32x4 oacc[8] = {};

  auto stageK = [&](int tile, int b) {
    const int kb = tile * 64;
#pragma unroll
    for (int i = 0; i < 4; ++i) {
      int chunk = i * 256 + tid;          // 16 chunks/row, 64 rows
      int r = chunk >> 4, c = chunk & 15;
      int cs = c ^ (r & 7);
      gload_lds16(Kbase + (size_t)(kb + r) * Dh + cs * 8,
                  (bf16*)Ks + b * 8192 + (i * 256 + w * 64) * 8);
    }
  };
  auto stageV = [&](int tile, int b) {
    const int kb = tile * 64;
#pragma unroll
    for (int i = 0; i < 4; ++i) {
      int chunk = i * 256 + tid;          // 8 chunks/row, 128 rows
      int r = chunk >> 3, c = chunk & 7;
      int cs = c ^ (r & 7);
      gload_lds16(Vbase + (size_t)r * S + kb + cs * 8,
                  (bf16*)Vs + b * 8192 + (i * 256 + w * 64) * 8);
    }
  };

  stageK(t0, 0);
  stageV(t0, 0);
  __syncthreads();   // drain stage(t0)
  int buf = 0;

  for (int t = t0; t < t1; ++t) {
    if (t + 1 < t1) { stageK(t + 1, buf ^ 1); stageV(t + 1, buf ^ 1); }  // async

    // ---- QK^T (swapped): sacc[jn][i] = S[k = jn*16+lq*4+i][q = lr] ----
    f32x4 sacc[4] = {};
    __builtin_amdgcn_s_setprio(1);
#pragma unroll
    for (int jn = 0; jn < 4; ++jn) {
      int r = jn * 16 + lr;
      const char* kroww = (const char*)Ks + buf * 16384 + r * 256;
      int rx = r & 7;
#pragma unroll
      for (int dd = 0; dd < 4; ++dd) {
        int cg = (dd * 4 + lq) ^ rx;
        short8 kf = *reinterpret_cast<const short8*>(kroww + cg * 16);
        sacc[jn] = MFMA16(kf, qf[dd], sacc[jn]);   // A=K, B=Q
      }
    }
    __builtin_amdgcn_s_setprio(0);

    // ---- mask + per-lane row max (q-row = w*16 + lr) ----
    const bool diag = (t == qi);
    float p[4][4];
    float pm = NEG_BIG;
#pragma unroll
    for (int jn = 0; jn < 4; ++jn)
#pragma unroll
      for (int i = 0; i < 4; ++i) {
        float v = sacc[jn][i];
        if (diag && (jn * 16 + lq * 4 + i > w * 16 + lr)) v = NEG_BIG;
        p[jn][i] = v;
        pm = fmaxf(pm, v);
      }
    pm = fmaxf(pm, __shfl_xor(pm, 16));
    pm = fmaxf(pm, __shfl_xor(pm, 32));

    // defer-max rescale (wave-uniform branch)
    if (!__all(pm - m <= 8.0f)) {
      float mnew = fmaxf(m, pm);
      float a = __expf(m - mnew);
      m = mnew;
      float aq[4];
#pragma unroll
      for (int i = 0; i < 4; ++i) aq[i] = __shfl(a, lq * 4 + i);
#pragma unroll
      for (int i = 0; i < 4; ++i) {
        lacc[i] *= aq[i];
#pragma unroll
        for (int jd = 0; jd < 8; ++jd) oacc[jd][i] *= aq[i];
      }
    }

    // ---- exp + pack to bf16 pairs ----
    unsigned int wd[4][2];
#pragma unroll
    for (int jn = 0; jn < 4; ++jn)
#pragma unroll
      for (int uu = 0; uu < 2; ++uu) {
        float plo = __expf(p[jn][2 * uu] - m);
        float phi = __expf(p[jn][2 * uu + 1] - m);
        wd[jn][uu] = pack_bf16(plo, phi);
      }

    // ---- P exchange via per-wave swizzled LDS ----
    // store: row lr, logical col jn*16+lq*4 (8 B) at slot (jn*2+(lq>>1))^(lr&7)
#pragma unroll
    for (int jn = 0; jn < 4; ++jn) {
      int slot = jn * 2 + (lq >> 1);
      *reinterpret_cast<uint2*>(Pw + lr * 128 + ((slot ^ (lr & 7)) * 16 + (lq & 1) * 8)) =
          make_uint2(wd[jn][0], wd[jn][1]);
    }
    __builtin_amdgcn_wave_barrier();
    // read: pa[kk] = P[q=lr][k = kk*32+lq*8 .. +7], slot (kk*4+lq)^(lr&7)
    short8 pa[2];
#pragma unroll
    for (int kk = 0; kk < 2; ++kk) {
      int slot = kk * 4 + lq;
      pa[kk] = *reinterpret_cast<const short8*>(Pw + lr * 128 + ((slot ^ (lr & 7)) * 16));
    }

    // ---- O += P @ V; denominator via ones-MFMA ----
    __builtin_amdgcn_s_setprio(1);
#pragma unroll
    for (int kk = 0; kk < 2; ++kk) {
      lacc = MFMA16(pa[kk], ones, lacc);
#pragma unroll
      for (int jd = 0; jd < 8; ++jd) {
        int r = jd * 16 + lr;
        int cg = (kk * 4 + lq) ^ (r & 7);
        short8 vf = *reinterpret_cast<const short8*>((const char*)Vs + buf * 16384 + r * 128 + cg * 16);
        oacc[jd] = MFMA16(pa[kk], vf, oacc[jd]);
      }
    }
    __builtin_amdgcn_s_setprio(0);

    __syncthreads();  // drains stage(t+1) into buf^1; orders P reuse; reads of buf done
    buf ^= 1;
  }

  if (nc == 1) {
#pragma unroll
    for (int jd = 0; jd < 8; ++jd)
#pragma unroll
      for (int i = 0; i < 4; ++i) {
        float o = oacc[jd][i] / lacc[i];
        AO[(size_t)(q0 + w * 16 + lq * 4 + i) * E + h * Dh + jd * 16 + lr] = __float2bfloat16(o);
      }
  } else {
    const int pidx = h * 80 + u;
    bf16* Op = Opart + (size_t)pidx * 64 * 128;
#pragma unroll
    for (int jd = 0; jd < 8; ++jd)
#pragma unroll
      for (int i = 0; i < 4; ++i)
        Op[(w * 16 + lq * 4 + i) * 128 + jd * 16 + lr] = __float2bfloat16(oacc[jd][i]);
    if (lq == 0)
      ml[(size_t)pidx * 128 + (w * 16 + lr) * 2] = m;          // m for q-row lr
    if (lr == 0) {
#pragma unroll
      for (int i = 0; i < 4; ++i)
        ml[(size_t)pidx * 128 + (w * 16 + lq * 4 + i) * 2 + 1] = lacc[i];
    }
  }
}

// ---------------- combine partial chunks (qi >= 8) -----------------------------
__global__ __launch_bounds__(256) void attn_combine(const bf16* __restrict__ Opart,
                                                    const float* __restrict__ ml,
                                                    bf16* __restrict__ AO) {
  const int qi = 8 + blockIdx.x;
  const int h = blockIdx.y;
  const int nc = qi / 8 + 1;
  const int off = (qi < 16) ? 8 + (qi - 8) * 2
                : (qi < 24) ? 24 + (qi - 16) * 3
                            : 48 + (qi - 24) * 4;
  const int base = h * 80 + off;
  const int row = threadIdx.x >> 2;
  const int d0 = (threadIdx.x & 3) * 32;

  float mc[4], lc[4];
  float M = -INFINITY;
  for (int c = 0; c < nc; ++c) {
    mc[c] = ml[(size_t)(base + c) * 128 + row * 2];
    lc[c] = ml[(size_t)(base + c) * 128 + row * 2 + 1];
    M = fmaxf(M, mc[c]);
  }
  float L = 0.0f;
  float acc[32];
#pragma unroll
  for (int j = 0; j < 32; ++j) acc[j] = 0.0f;
  for (int c = 0; c < nc; ++c) {
    float wgt = __expf(mc[c] - M);
    L += wgt * lc[c];
    const short8* op = reinterpret_cast<const short8*>(
        Opart + (size_t)(base + c) * 8192 + row * 128 + d0);
#pragma unroll
    for (int j4 = 0; j4 < 4; ++j4) {
      short8 vv = op[j4];
#pragma unroll
      for (int e = 0; e < 8; ++e) {
        short sv = vv[e];
        acc[j4 * 8 + e] += wgt * __bfloat162float(*reinterpret_cast<bf16*>(&sv));
      }
    }
  }
  float inv = 1.0f / L;
  bf16* ao = AO + (size_t)(qi * 64 + row) * E + h * Dh + d0;
  short8 outv[4];
#pragma unroll
  for (int j4 = 0; j4 < 4; ++j4) {
#pragma unroll
    for (int e = 0; e < 8; ++e) outv[j4][e] = f2bs(acc[j4 * 8 + e] * inv);
    reinterpret_cast<short8*>(ao)[j4] = outv[j4];
  }
}

// ------------------------------------------------------------------------------
extern "C" void kernel_launch(void* const* d_in, const int* in_sizes, int n_in,
                              void* d_out, int out_size, void* d_ws, size_t ws_size,
                              hipStream_t stream) {
  const float* x  = (const float*)d_in[0];
  const float* Wq = (const float*)d_in[2];
  const float* Wk = (const float*)d_in[3];
  const float* Wv = (const float*)d_in[4];
  const float* Wo = (const float*)d_in[5];
  const float* qw = (const float*)d_in[6];
  const float* kw = (const float*)d_in[7];

  char* ws = (char*)d_ws;
  bf16* xb   = (bf16*)(ws + (0ull << 20));    // [2048][2048]   8 MB   (dead after GEMM1)
  bf16* Wcat = (bf16*)(ws + (8ull << 20));    // [3072][2048]  12 MB   (dead after GEMM1)
  bf16* Wob  = (bf16*)(ws + (20ull << 20));   // [2048][2048]   8 MB
  bf16* QKV  = (bf16*)(ws + (28ull << 20));   // [2048][3072]  12 MB   (dead after norm/transpose)
  bf16* Qn   = (bf16*)(ws + (40ull << 20));   // [16][2048][128] 8 MB
  bf16* Kn   = (bf16*)(ws + (48ull << 20));   // [4][2048][128]  2 MB
  bf16* Vt   = (bf16*)(ws + (50ull << 20));   // [4][128][2048]  2 MB
  bf16* AO   = (bf16*)(ws + (52ull << 20));   // [2048][2048]    8 MB
  bf16* Opart = (bf16*)(ws + (0ull << 20));   // 1280 x [64][128] = 20 MB, reuses xb+Wcat
  float* ml   = (float*)(ws + (28ull << 20)); // 1280 x 128 f32 = 640 KB, reuses QKV

  cvt_all<<<7168, 256, 0, stream>>>(x, Wq, Wk, Wv, Wo, xb, Wcat, Wob);

  gemm_nt<false><<<dim3(S / 128, NQKV / 128), 256, 0, stream>>>(xb, Wcat, QKV, S, NQKV, E);

  qk_norm_rope_vt<<<10240 + 256, 256, 0, stream>>>(QKV, qw, kw, Qn, Kn, Vt);

  attn_fwd<<<16 * 80, 256, 0, stream>>>(Qn, Kn, Vt, AO, Opart, ml);
  attn_combine<<<dim3(24, 16), 256, 0, stream>>>(Opart, ml, AO);

  gemm_nt64<<<dim3(S / 128, E / 64), 256, 0, stream>>>(AO, Wob, (float*)d_out, S, E, E);
}